// Round 7
// baseline (495.317 us; speedup 1.0000x reference)
//
#include <hip/hip_runtime.h>
#include <cstdint>
#include <cstddef>

#define U_NODES 100000
#define V_NODES 50000
#define N_EDGES 2000000
#define NSEG_CAP 25

// dims: F=32 (u), G=32 (v), H=8 (edge); g: 72->64->32 ; f: 64->64->32 ; tail 32->1
// g_w1 rows: [0,32) u-part, [32,64) v-part, [64,72) edge-val part.

typedef _Float16 f16x8 __attribute__((ext_vector_type(8)));
typedef _Float16 f16x2 __attribute__((ext_vector_type(2)));
typedef float    f32x4 __attribute__((ext_vector_type(4)));

__device__ __forceinline__ void load8f(const float* __restrict__ p, float* x) {
    const float4* p4 = reinterpret_cast<const float4*>(p);
    float4 a = p4[0], b = p4[1];
    x[0]=a.x; x[1]=a.y; x[2]=a.z; x[3]=a.w;
    x[4]=b.x; x[5]=b.y; x[6]=b.z; x[7]=b.w;
}

__device__ __forceinline__ void load32f(const float* __restrict__ p, float* x) {
    #pragma unroll
    for (int q = 0; q < 4; ++q) load8f(p + 8*q, x + 8*q);
}

__device__ __forceinline__ unsigned pack_bf16x2(float a, float b) {
    unsigned ua = __float_as_uint(a);
    ua = (ua + 0x7FFFu + ((ua >> 16) & 1u)) >> 16;
    unsigned ub = __float_as_uint(b);
    ub = (ub + 0x7FFFu + ((ub >> 16) & 1u)) & 0xFFFF0000u;
    return ua | ub;
}

__device__ __forceinline__ unsigned pk16(float a, float b) {
    union { f16x2 h; unsigned u; } c;
    c.h[0] = (_Float16)a; c.h[1] = (_Float16)b;
    return c.u;
}
__device__ __forceinline__ float f16lo(unsigned w) {
    union { unsigned short u; _Float16 h; } c; c.u = (unsigned short)(w & 0xFFFFu);
    return (float)c.h;
}
__device__ __forceinline__ float f16hi(unsigned w) {
    union { unsigned short u; _Float16 h; } c; c.u = (unsigned short)(w >> 16);
    return (float)c.h;
}
__device__ __forceinline__ f16x8 as_f16x8(uint4 x) {
    union { uint4 u; f16x8 h; } c; c.u = x; return c.h;
}

// fdot2: acc += a.lo*b.lo + a.hi*b.hi (f16 inputs, f32 accum)
__device__ __forceinline__ float fdot2f(unsigned a, unsigned b, float c) {
#if defined(__has_builtin) && __has_builtin(__builtin_amdgcn_fdot2)
    union { unsigned u; f16x2 h; } ca, cb; ca.u = a; cb.u = b;
    return __builtin_amdgcn_fdot2(ca.h, cb.h, c, false);
#else
    return c + f16lo(a)*f16lo(b) + f16hi(a)*f16hi(b);
#endif
}

// ---------------- pre-projection (A = u@W1u ; B = v@W1v + b1) ------------------

__global__ __launch_bounds__(256) void proj_u_kernel(
    const float* __restrict__ u, const float* __restrict__ g_w1,
    float* __restrict__ A)
{
    int n = blockIdx.x * 256 + threadIdx.x;
    if (n >= U_NODES) return;
    float x[32];
    load32f(u + (size_t)n * 32, x);
    float acc[64];
    #pragma unroll
    for (int j = 0; j < 64; ++j) acc[j] = 0.f;
    #pragma unroll
    for (int i = 0; i < 32; ++i) {
        #pragma unroll
        for (int j = 0; j < 64; ++j) acc[j] += x[i] * g_w1[i*64 + j];
    }
    float4* Ap = reinterpret_cast<float4*>(A + (size_t)n * 64);
    #pragma unroll
    for (int q = 0; q < 16; ++q)
        Ap[q] = make_float4(acc[4*q], acc[4*q+1], acc[4*q+2], acc[4*q+3]);
}

__global__ __launch_bounds__(256) void proj_v_kernel(
    const float* __restrict__ v, const float* __restrict__ g_w1,
    const float* __restrict__ g_b1, float* __restrict__ B)
{
    int n = blockIdx.x * 256 + threadIdx.x;
    if (n >= V_NODES) return;
    float x[32];
    load32f(v + (size_t)n * 32, x);
    float acc[64];
    #pragma unroll
    for (int j = 0; j < 64; ++j) acc[j] = g_b1[j];
    #pragma unroll
    for (int i = 0; i < 32; ++i) {
        #pragma unroll
        for (int j = 0; j < 64; ++j) acc[j] += x[i] * g_w1[(32+i)*64 + j];
    }
    float4* Bp = reinterpret_cast<float4*>(B + (size_t)n * 64);
    #pragma unroll
    for (int q = 0; q < 16; ++q)
        Bp[q] = make_float4(acc[4*q], acc[4*q+1], acc[4*q+2], acc[4*q+3]);
}

// ---------------- CSR build ----------------------------------------------------

__global__ __launch_bounds__(256) void rank_kernel(
    const int* __restrict__ e_dst, int* __restrict__ deg, int* __restrict__ rank)
{
    int e = blockIdx.x * 256 + threadIdx.x;
    if (e >= N_EDGES) return;
    rank[e] = atomicAdd(&deg[e_dst[e]], 1);
}

__global__ __launch_bounds__(256) void scan_block_kernel(
    const int* __restrict__ deg, int* __restrict__ off, int* __restrict__ aux, int n)
{
    __shared__ int s[256];
    int tid = threadIdx.x;
    int i = blockIdx.x * 256 + tid;
    int x = (i < n) ? deg[i] : 0;
    s[tid] = x;
    __syncthreads();
    #pragma unroll
    for (int o = 1; o < 256; o <<= 1) {
        int t = (tid >= o) ? s[tid - o] : 0;
        __syncthreads();
        s[tid] += t;
        __syncthreads();
    }
    if (i < n) off[i + 1] = s[tid];
    if (tid == 255) aux[blockIdx.x] = s[255];
}

__global__ __launch_bounds__(512) void scan_aux_kernel(int* __restrict__ aux, int nA)
{
    __shared__ int s[512];
    int tid = threadIdx.x;
    int x = (tid < nA) ? aux[tid] : 0;
    s[tid] = x;
    __syncthreads();
    #pragma unroll
    for (int o = 1; o < 512; o <<= 1) {
        int t = (tid >= o) ? s[tid - o] : 0;
        __syncthreads();
        s[tid] += t;
        __syncthreads();
    }
    if (tid < nA) aux[tid] = s[tid] - x;  // exclusive
}

__global__ __launch_bounds__(256) void scan_add_kernel(
    int* __restrict__ off, const int* __restrict__ aux, int n)
{
    int i = blockIdx.x * 256 + threadIdx.x;
    if (i == 0) off[0] = 0;
    if (i < n) off[i + 1] += aux[i >> 8];
}

__global__ __launch_bounds__(256) void scatter_kernel(
    const int* __restrict__ e_dst, const int* __restrict__ off,
    const int* __restrict__ rank, int* __restrict__ sorted_eid)
{
    int e = blockIdx.x * 256 + threadIdx.x;
    if (e >= N_EDGES) return;
    int d = e_dst[e];
    sorted_eid[off[d] + rank[e]] = e;
}

// packed 32B edge record: [d, s, ev16 x4, pad x2] -> ONE sector touch per edge
__global__ __launch_bounds__(256) void permute_pack_kernel(
    const int* __restrict__ e_dst, const int* __restrict__ e_src,
    const int* __restrict__ rank, const int* __restrict__ off,
    const float* __restrict__ e_vals, unsigned* __restrict__ epk)
{
    int e = blockIdx.x * 256 + threadIdx.x;
    if (e >= N_EDGES) return;
    int d = e_dst[e];
    int pos = off[d] + rank[e];
    float ev[8];
    load8f(e_vals + (size_t)e * 8, ev);
    uint4 w0;
    w0.x = (unsigned)d;
    w0.y = (unsigned)e_src[e];
    w0.z = pk16(ev[0], ev[1]);
    w0.w = pk16(ev[2], ev[3]);
    uint2 w1;
    w1.x = pk16(ev[4], ev[5]);
    w1.y = pk16(ev[6], ev[7]);
    unsigned* dst = epk + (size_t)pos * 8;
    *reinterpret_cast<uint4*>(dst)     = w0;
    *reinterpret_cast<uint2*>(dst + 4) = w1;
}

// ---- edge kernel: h1 computed directly in MFMA A-fragment registers ----------
// lane (lm=lane&15, lg=lane>>4) computes h1 cols [kt*32+lg*8, +8) for edges
// {wave*64 + mt*16 + lm}. MFMA 16x per wave. Wave-local segmented reduce into
// s_agg via ds_add; interior segs stored (sole writer); boundary segs stitched
// across the block's 4 waves after one barrier. LDS ~21.6KB, 2 barriers total.

__global__ __launch_bounds__(256) void edge_reg_kernel(
    const float* __restrict__ A, const float* __restrict__ B,
    const unsigned* __restrict__ epk,
    const float* __restrict__ g_w1, const float* __restrict__ g_w2,
    const float* __restrict__ g_b2, float* __restrict__ agg)
{
    __shared__ unsigned s_w2[32 * 33];                  // f16x2 W2 [kp][n]
    __shared__ __align__(16) unsigned s_w1e[4 * 64];    // f16x2 W1e row-pairs [i2][c]
    __shared__ int   s_d[256];
    __shared__ int   s_meta[4][64];                     // seg -> start lane
    __shared__ float s_agg[4][NSEG_CAP][33];
    __shared__ float pub_val[4][2][32];
    __shared__ int   pub_d[4][2];
    __shared__ int   pub_fl[4][2];
    __shared__ int   s_bprev, s_bnext;

    const int tid = threadIdx.x;
    const long bP = (long)blockIdx.x * 256;

    // stage W2 as f16 pairs
    #pragma unroll
    for (int i = 0; i < 4; ++i) {
        int idx = tid + i * 256;
        int kp = idx >> 5, n = idx & 31;
        s_w2[kp * 33 + n] = pk16(g_w2[(2*kp)*32 + n], g_w2[(2*kp+1)*32 + n]);
    }
    // stage W1e row-pairs (rows 64..71 of g_w1)
    {
        int i2 = tid >> 6, c = tid & 63;
        s_w1e[i2 * 64 + c] = pk16(g_w1[(64 + 2*i2)*64 + c], g_w1[(64 + 2*i2 + 1)*64 + c]);
    }
    if (tid == 0) {
        s_bprev = (bP > 0) ? (int)epk[(size_t)(bP - 1) * 8] : -2;
        s_bnext = (bP + 256 < (long)N_EDGES) ? (int)epk[(size_t)(bP + 256) * 8] : -2;
    }
    __syncthreads();

    const int wv   = tid >> 6;
    const int lane = tid & 63;
    const int lm   = lane & 15;
    const int lg   = lane >> 4;
    const long wP  = bP + wv * 64;

    // load my 4 edges' records
    int dM[4], sM[4];
    unsigned evp[4][4];
    #pragma unroll
    for (int mt = 0; mt < 4; ++mt) {
        long pe = wP + mt*16 + lm;
        if (pe < (long)N_EDGES) {
            const unsigned* ep = epk + (size_t)pe * 8;
            uint4 w0 = *reinterpret_cast<const uint4*>(ep);
            uint2 w1 = *reinterpret_cast<const uint2*>(ep + 4);
            dM[mt] = (int)w0.x; sM[mt] = (int)w0.y;
            evp[mt][0] = w0.z; evp[mt][1] = w0.w; evp[mt][2] = w1.x; evp[mt][3] = w1.y;
        } else {
            dM[mt] = -1; sM[mt] = 0;
            evp[mt][0] = evp[mt][1] = evp[mt][2] = evp[mt][3] = 0;
        }
    }
    if (lg == 0) {
        #pragma unroll
        for (int mt = 0; mt < 4; ++mt) s_d[wv*64 + mt*16 + lm] = dM[mt];
    }
    // zero own wave's s_agg region
    {
        float* z = &s_agg[wv][0][0];
        for (int i = lane; i < NSEG_CAP * 33; i += 64) z[i] = 0.f;
    }

    // ---- h1 -> A fragments (in registers) ----
    uint4 afr[4][2];
    #pragma unroll
    for (int kt = 0; kt < 2; ++kt) {
        float acc[4][8];
        #pragma unroll
        for (int mt = 0; mt < 4; ++mt) {
            if (dM[mt] >= 0) {
                const float4* Ap = reinterpret_cast<const float4*>(A + (size_t)dM[mt]*64 + kt*32 + lg*8);
                const float4* Bp = reinterpret_cast<const float4*>(B + (size_t)sM[mt]*64 + kt*32 + lg*8);
                float4 a0 = Ap[0], a1 = Ap[1], b0 = Bp[0], b1 = Bp[1];
                acc[mt][0] = a0.x + b0.x; acc[mt][1] = a0.y + b0.y;
                acc[mt][2] = a0.z + b0.z; acc[mt][3] = a0.w + b0.w;
                acc[mt][4] = a1.x + b1.x; acc[mt][5] = a1.y + b1.y;
                acc[mt][6] = a1.z + b1.z; acc[mt][7] = a1.w + b1.w;
            } else {
                #pragma unroll
                for (int j = 0; j < 8; ++j) acc[mt][j] = 0.f;
            }
        }
        #pragma unroll
        for (int i2 = 0; i2 < 4; ++i2) {
            uint4 wA = *reinterpret_cast<const uint4*>(&s_w1e[i2*64 + kt*32 + lg*8]);
            uint4 wB = *reinterpret_cast<const uint4*>(&s_w1e[i2*64 + kt*32 + lg*8 + 4]);
            unsigned wp0 = wA.x, wp1 = wA.y, wp2 = wA.z, wp3 = wA.w;
            unsigned wp4 = wB.x, wp5 = wB.y, wp6 = wB.z, wp7 = wB.w;
            #pragma unroll
            for (int mt = 0; mt < 4; ++mt) {
                unsigned e2 = evp[mt][i2];
                acc[mt][0] = fdot2f(e2, wp0, acc[mt][0]);
                acc[mt][1] = fdot2f(e2, wp1, acc[mt][1]);
                acc[mt][2] = fdot2f(e2, wp2, acc[mt][2]);
                acc[mt][3] = fdot2f(e2, wp3, acc[mt][3]);
                acc[mt][4] = fdot2f(e2, wp4, acc[mt][4]);
                acc[mt][5] = fdot2f(e2, wp5, acc[mt][5]);
                acc[mt][6] = fdot2f(e2, wp6, acc[mt][6]);
                acc[mt][7] = fdot2f(e2, wp7, acc[mt][7]);
            }
        }
        #pragma unroll
        for (int mt = 0; mt < 4; ++mt) {
            uint4 w;
            w.x = pk16(fmaxf(acc[mt][0], 0.f), fmaxf(acc[mt][1], 0.f));
            w.y = pk16(fmaxf(acc[mt][2], 0.f), fmaxf(acc[mt][3], 0.f));
            w.z = pk16(fmaxf(acc[mt][4], 0.f), fmaxf(acc[mt][5], 0.f));
            w.w = pk16(fmaxf(acc[mt][6], 0.f), fmaxf(acc[mt][7], 0.f));
            afr[mt][kt] = w;
        }
    }

    // ---- MFMA: [64 x 64] @ [64 x 32] ----
    f32x4 mac[4][2];
    #pragma unroll
    for (int mt = 0; mt < 4; ++mt) {
        #pragma unroll
        for (int nt = 0; nt < 2; ++nt) {
            mac[mt][nt][0] = 0.f; mac[mt][nt][1] = 0.f;
            mac[mt][nt][2] = 0.f; mac[mt][nt][3] = 0.f;
        }
    }
    #pragma unroll
    for (int kt = 0; kt < 2; ++kt) {
        uint4 bf0, bf1;
        int kp = kt*16 + lg*4;
        bf0.x = s_w2[(kp+0)*33 + lm];      bf1.x = s_w2[(kp+0)*33 + 16 + lm];
        bf0.y = s_w2[(kp+1)*33 + lm];      bf1.y = s_w2[(kp+1)*33 + 16 + lm];
        bf0.z = s_w2[(kp+2)*33 + lm];      bf1.z = s_w2[(kp+2)*33 + 16 + lm];
        bf0.w = s_w2[(kp+3)*33 + lm];      bf1.w = s_w2[(kp+3)*33 + 16 + lm];
        f16x8 b0 = as_f16x8(bf0), b1 = as_f16x8(bf1);
        #pragma unroll
        for (int mt = 0; mt < 4; ++mt) {
            f16x8 a = as_f16x8(afr[mt][kt]);
            mac[mt][0] = __builtin_amdgcn_mfma_f32_16x16x32_f16(a, b0, mac[mt][0], 0, 0, 0);
            mac[mt][1] = __builtin_amdgcn_mfma_f32_16x16x32_f16(a, b1, mac[mt][1], 0, 0, 0);
        }
    }

    // ---- wave-local segmented reduce ----
    asm volatile("s_waitcnt lgkmcnt(0)" ::: "memory");   // s_d + zeros visible

    int myd = s_d[wv*64 + lane];
    int prevd = (lane > 0) ? s_d[wv*64 + lane - 1] : -2;
    bool headb = (lane == 0) || (myd != prevd);
    unsigned long long mask = __ballot(headb);

    long remaining = (long)N_EDGES - wP;
    int validcnt = remaining >= 64 ? 64 : (remaining < 0 ? 0 : (int)remaining);
    unsigned long long vmask = (validcnt >= 64) ? ~0ull : ((1ull << validcnt) - 1ull);
    int nsegV = (int)__popcll(mask & vmask);

    if (headb && lane < validcnt) {
        int sg = (int)__popcll(mask & ((2ull << lane) - 1ull)) - 1;
        s_meta[wv][sg] = lane;
    }

    float b2a = g_b2[lm], b2b = g_b2[16 + lm];

    #pragma unroll
    for (int mt = 0; mt < 4; ++mt) {
        const int ebase = mt*16 + lg*4;
        float v0[4], v1[4];
        #pragma unroll
        for (int r = 0; r < 4; ++r) {
            v0[r] = fmaxf(mac[mt][0][r] + b2a, 0.f);
            v1[r] = fmaxf(mac[mt][1][r] + b2b, 0.f);
        }
        float cs0 = v0[0], cs1 = v1[0];
        int rstart = 0;
        #pragma unroll
        for (int r = 1; r <= 4; ++r) {
            bool cut = (r == 4) || (((mask >> (ebase + r)) & 1ull) != 0);
            if (cut) {
                int e0 = ebase + rstart;
                int dd = s_d[wv*64 + e0];
                if (dd >= 0) {
                    int sg = (int)__popcll(mask & ((2ull << e0) - 1ull)) - 1;
                    if (sg < NSEG_CAP) {
                        atomicAdd(&s_agg[wv][sg][lm], cs0);
                        atomicAdd(&s_agg[wv][sg][16 + lm], cs1);
                    } else {
                        atomicAdd(agg + (size_t)dd*32 + lm, cs0);
                        atomicAdd(agg + (size_t)dd*32 + 16 + lm, cs1);
                    }
                }
                if (r < 4) { rstart = r; cs0 = v0[r]; cs1 = v1[r]; }
            } else {
                cs0 += v0[r]; cs1 += v1[r];
            }
        }
    }

    asm volatile("s_waitcnt lgkmcnt(0)" ::: "memory");   // ds_adds + s_meta done

    // interior segments: sole-writer stores
    int nI = (nsegV - 1 < NSEG_CAP ? nsegV - 1 : NSEG_CAP) - 1;  // segs 1..nI
    for (int it = lane; it < nI * 32; it += 64) {
        int sg = 1 + (it >> 5);
        int c  = it & 31;
        int dd = s_d[wv*64 + s_meta[wv][sg]];
        agg[(size_t)dd*32 + c] = s_agg[wv][sg][c];
    }

    // publish boundary segments (slot0 = seg 0, slot1 = seg nsegV-1 if distinct)
    if (lane < 32) {
        int c = lane;
        if (nsegV >= 1) {
            pub_val[wv][0][c] = s_agg[wv][0][c];
            if (c == 0) { pub_d[wv][0] = s_d[wv*64]; pub_fl[wv][0] = 0; }
        } else if (c == 0) { pub_d[wv][0] = -3; pub_fl[wv][0] = 0; }
    } else {
        int c = lane - 32;
        if (nsegV >= 2) {
            int sL = nsegV - 1;
            if (sL < NSEG_CAP) {
                pub_val[wv][1][c] = s_agg[wv][sL][c];
                if (c == 0) { pub_d[wv][1] = s_d[wv*64 + s_meta[wv][sL]]; pub_fl[wv][1] = 0; }
            } else {
                pub_val[wv][1][c] = 0.f;   // already added atomically (overflow path)
                if (c == 0) { pub_d[wv][1] = s_d[wv*64 + s_meta[wv][sL]]; pub_fl[wv][1] = 1; }
            }
        } else if (c == 0) { pub_d[wv][1] = -3; pub_fl[wv][1] = 0; }
    }
    __syncthreads();

    // stitch across the block's 4 waves (32 lanes, one per channel)
    if (tid < 32) {
        const int c = tid;
        int firstV = -1, lastV = -1;
        #pragma unroll
        for (int k = 0; k < 8; ++k) {
            int dk = pub_d[k >> 1][k & 1];
            if (dk >= 0) { if (firstV < 0) firstV = k; lastV = k; }
        }
        int k = firstV;
        while (firstV >= 0 && k <= lastV) {
            int dk = pub_d[k >> 1][k & 1];
            if (dk < 0) { ++k; continue; }
            int d0 = dk; int kst = k;
            float s = 0.f; int atm = 0;
            while (k <= lastV) {
                int d2 = pub_d[k >> 1][k & 1];
                if (d2 == d0) {
                    s += pub_val[k >> 1][k & 1][c];
                    atm |= pub_fl[k >> 1][k & 1];
                    ++k;
                } else if (d2 < 0) { ++k; }
                else break;
            }
            bool lo = (kst == firstV) && (s_bprev == d0);
            bool ro = (k > lastV) && (s_bnext == d0);
            float* dst = agg + (size_t)d0*32 + c;
            if (lo || ro || atm) atomicAdd(dst, s);
            else *dst = s;
        }
    }
}

// ------- fallback tier-2: round-6 kernel (B precomputed, u-part on the fly) ----

template <bool HAS_A>
__global__ __launch_bounds__(256) void edge_mfma_kernel(
    const float* __restrict__ A, const float* __restrict__ B,
    const float* __restrict__ u, const unsigned* __restrict__ epk,
    const float* __restrict__ g_w1, const float* __restrict__ g_w2,
    const float* __restrict__ g_b2, float* __restrict__ agg)
{
    __shared__ unsigned s_h1[256 * 36];
    __shared__ unsigned s_w2[32 * 33];
    __shared__ int s_d[256];
    __shared__ int s_heads[256];
    __shared__ int s_cnt, s_prevd, s_nextd;

    const int tid = threadIdx.x;
    const long p = (long)blockIdx.x * 256 + tid;

    if (tid == 0) {
        s_cnt = 0;
        long pprev = (long)blockIdx.x * 256 - 1;
        s_prevd = (pprev < 0) ? -2 : (int)epk[(size_t)pprev * 8];
        long pnext = (long)blockIdx.x * 256 + 256;
        s_nextd = (pnext >= N_EDGES) ? -2 : (int)epk[(size_t)pnext * 8];
    }
    #pragma unroll
    for (int i = 0; i < 4; ++i) {
        int idx = tid + i * 256;
        int kp = idx >> 5, n = idx & 31;
        s_w2[kp * 33 + n] = pk16(g_w2[(2*kp)*32 + n], g_w2[(2*kp+1)*32 + n]);
    }

    int d = -1;
    if (p < N_EDGES) {
        const unsigned* ep = epk + (size_t)p * 8;
        uint4 w0 = *reinterpret_cast<const uint4*>(ep);
        uint2 w1 = *reinterpret_cast<const uint2*>(ep + 4);
        d = (int)w0.x;
        int s = (int)w0.y;

        float h1[64];
        if constexpr (HAS_A) {
            const float4* Ap = reinterpret_cast<const float4*>(A + (size_t)d * 64);
            #pragma unroll
            for (int q = 0; q < 16; ++q) {
                float4 a = Ap[q];
                h1[4*q+0] = a.x; h1[4*q+1] = a.y; h1[4*q+2] = a.z; h1[4*q+3] = a.w;
            }
        } else {
            #pragma unroll
            for (int j = 0; j < 64; ++j) h1[j] = 0.f;
            float x[32];
            load32f(u + (size_t)d * 32, x);
            #pragma unroll
            for (int i = 0; i < 32; ++i) {
                #pragma unroll
                for (int j = 0; j < 64; ++j) h1[j] += x[i] * g_w1[i*64 + j];
            }
        }
        {
            const float4* Bp = reinterpret_cast<const float4*>(B + (size_t)s * 64);
            #pragma unroll
            for (int q = 0; q < 16; ++q) {
                float4 b = Bp[q];
                h1[4*q+0] += b.x; h1[4*q+1] += b.y; h1[4*q+2] += b.z; h1[4*q+3] += b.w;
            }
        }
        float ev[8];
        ev[0]=f16lo(w0.z); ev[1]=f16hi(w0.z); ev[2]=f16lo(w0.w); ev[3]=f16hi(w0.w);
        ev[4]=f16lo(w1.x); ev[5]=f16hi(w1.x); ev[6]=f16lo(w1.y); ev[7]=f16hi(w1.y);
        #pragma unroll
        for (int i = 0; i < 8; ++i) {
            #pragma unroll
            for (int j = 0; j < 64; ++j) h1[j] += ev[i] * g_w1[(64+i)*64 + j];
        }
        #pragma unroll
        for (int j = 0; j < 64; ++j) h1[j] = fmaxf(h1[j], 0.f);

        #pragma unroll
        for (int q = 0; q < 8; ++q) {
            uint4 w;
            w.x = pk16(h1[8*q+0], h1[8*q+1]);
            w.y = pk16(h1[8*q+2], h1[8*q+3]);
            w.z = pk16(h1[8*q+4], h1[8*q+5]);
            w.w = pk16(h1[8*q+6], h1[8*q+7]);
            *reinterpret_cast<uint4*>(&s_h1[tid*36 + 4*q]) = w;
        }
    }
    s_d[tid] = d;
    __syncthreads();

    if (p < N_EDGES) {
        int prevd = (tid == 0) ? s_prevd : s_d[tid - 1];
        bool true_head = (prevd != d);
        bool is_head = (tid == 0) || true_head;
        if (is_head) {
            int idx = atomicAdd(&s_cnt, 1);
            s_heads[idx] = tid | (true_head ? 0x10000 : 0);
        }
    }

    const int lane = tid & 63;
    const int wb   = (tid >> 6) * 64;
    const int lg   = lane >> 4;
    const int lm   = lane & 15;

    f32x4 acc[4][2];
    #pragma unroll
    for (int mt = 0; mt < 4; ++mt) {
        #pragma unroll
        for (int nt = 0; nt < 2; ++nt) {
            acc[mt][nt][0] = 0.f; acc[mt][nt][1] = 0.f;
            acc[mt][nt][2] = 0.f; acc[mt][nt][3] = 0.f;
        }
    }
    #pragma unroll
    for (int kt = 0; kt < 2; ++kt) {
        uint4 bf0, bf1;
        int kp = kt*16 + lg*4;
        bf0.x = s_w2[(kp+0)*33 + lm];      bf1.x = s_w2[(kp+0)*33 + 16 + lm];
        bf0.y = s_w2[(kp+1)*33 + lm];      bf1.y = s_w2[(kp+1)*33 + 16 + lm];
        bf0.z = s_w2[(kp+2)*33 + lm];      bf1.z = s_w2[(kp+2)*33 + 16 + lm];
        bf0.w = s_w2[(kp+3)*33 + lm];      bf1.w = s_w2[(kp+3)*33 + 16 + lm];
        f16x8 b0 = as_f16x8(bf0), b1 = as_f16x8(bf1);
        #pragma unroll
        for (int mt = 0; mt < 4; ++mt) {
            uint4 av = *reinterpret_cast<const uint4*>(
                &s_h1[(wb + mt*16 + lm)*36 + kt*16 + lg*4]);
            f16x8 a = as_f16x8(av);
            acc[mt][0] = __builtin_amdgcn_mfma_f32_16x16x32_f16(a, b0, acc[mt][0], 0, 0, 0);
            acc[mt][1] = __builtin_amdgcn_mfma_f32_16x16x32_f16(a, b1, acc[mt][1], 0, 0, 0);
        }
    }
    float b2a = g_b2[lm];
    float b2b = g_b2[16 + lm];
    __syncthreads();

    float* h2f = reinterpret_cast<float*>(s_h1);
    #pragma unroll
    for (int mt = 0; mt < 4; ++mt) {
        #pragma unroll
        for (int r = 0; r < 4; ++r) {
            int row = wb + mt*16 + lg*4 + r;
            h2f[row*36 + lm]      = fmaxf(acc[mt][0][r] + b2a, 0.f);
            h2f[row*36 + 16 + lm] = fmaxf(acc[mt][1][r] + b2b, 0.f);
        }
    }
    __syncthreads();

    const int nseg = s_cnt;
    const int next_d = s_nextd;
    for (int w = tid; w < nseg * 16; w += 256) {
        int seg = w >> 4, cp = w & 15;
        int ent = s_heads[seg];
        int h = ent & 0xFFFF;
        bool thead = (ent & 0x10000) != 0;
        int dd = s_d[h];
        float s0 = 0.f, s1 = 0.f;
        int r = h;
        while (r < 256 && s_d[r] == dd) {
            s0 += h2f[r*36 + 2*cp];
            s1 += h2f[r*36 + 2*cp + 1];
            ++r;
        }
        bool end_complete = (r < 256) || (next_d != dd);
        float* dst = agg + (size_t)dd * 32 + 2 * cp;
        if (thead && end_complete) {
            *reinterpret_cast<float2*>(dst) = make_float2(s0, s1);
        } else {
            atomicAdd(dst + 0, s0);
            atomicAdd(dst + 1, s1);
        }
    }
}

// ------- fallback: edge MLP via seid gathers (round-4 proven path) --------------

template <bool HAS_A, bool HAS_B>
__global__ __launch_bounds__(256) void edge_sorted_kernel(
    const float* __restrict__ A, const float* __restrict__ B,
    const float* __restrict__ u, const float* __restrict__ v,
    const float* __restrict__ e_vals, const int* __restrict__ e_src,
    const int* __restrict__ e_dst, const int* __restrict__ seid,
    const float* __restrict__ g_w1, const float* __restrict__ g_b1,
    const float* __restrict__ g_w2, const float* __restrict__ g_b2,
    float* __restrict__ agg)
{
    __shared__ unsigned lds_h[256][17];
    __shared__ int lds_d[256];
    __shared__ int lds_heads[256];
    __shared__ int lds_cnt;
    __shared__ int lds_prev_d, lds_next_d;

    const int tid = threadIdx.x;
    const long p = (long)blockIdx.x * 256 + tid;

    if (tid == 0) {
        lds_cnt = 0;
        long pprev = (long)blockIdx.x * 256 - 1;
        lds_prev_d = (pprev < 0) ? -2 : e_dst[seid[pprev]];
        long pnext = (long)blockIdx.x * 256 + 256;
        lds_next_d = (pnext >= N_EDGES) ? -2 : e_dst[seid[pnext]];
    }

    int d = -1;
    if (p < N_EDGES) {
        int eid = seid[p];
        d = e_dst[eid];
        int s = e_src[eid];

        float h1[64];
        if constexpr (HAS_A) {
            const float4* Ap = reinterpret_cast<const float4*>(A + (size_t)d * 64);
            #pragma unroll
            for (int q = 0; q < 16; ++q) {
                float4 a = Ap[q];
                h1[4*q+0] = a.x; h1[4*q+1] = a.y; h1[4*q+2] = a.z; h1[4*q+3] = a.w;
            }
        } else {
            #pragma unroll
            for (int j = 0; j < 64; ++j) h1[j] = 0.f;
            float x[32];
            load32f(u + (size_t)d * 32, x);
            #pragma unroll
            for (int i = 0; i < 32; ++i) {
                #pragma unroll
                for (int j = 0; j < 64; ++j) h1[j] += x[i] * g_w1[i*64 + j];
            }
        }
        if constexpr (HAS_B) {
            const float4* Bp = reinterpret_cast<const float4*>(B + (size_t)s * 64);
            #pragma unroll
            for (int q = 0; q < 16; ++q) {
                float4 b = Bp[q];
                h1[4*q+0] += b.x; h1[4*q+1] += b.y; h1[4*q+2] += b.z; h1[4*q+3] += b.w;
            }
        } else {
            #pragma unroll
            for (int j = 0; j < 64; ++j) h1[j] += g_b1[j];
            float x[32];
            load32f(v + (size_t)s * 32, x);
            #pragma unroll
            for (int i = 0; i < 32; ++i) {
                #pragma unroll
                for (int j = 0; j < 64; ++j) h1[j] += x[i] * g_w1[(32+i)*64 + j];
            }
        }
        float ev[8];
        load8f(e_vals + (size_t)eid * 8, ev);
        #pragma unroll
        for (int i = 0; i < 8; ++i) {
            #pragma unroll
            for (int j = 0; j < 64; ++j) h1[j] += ev[i] * g_w1[(64+i)*64 + j];
        }
        #pragma unroll
        for (int j = 0; j < 64; ++j) h1[j] = fmaxf(h1[j], 0.f);

        float h2[32];
        #pragma unroll
        for (int k = 0; k < 32; ++k) h2[k] = g_b2[k];
        #pragma unroll
        for (int i = 0; i < 64; ++i) {
            #pragma unroll
            for (int k = 0; k < 32; ++k) h2[k] += h1[i] * g_w2[i*32 + k];
        }
        #pragma unroll
        for (int cp = 0; cp < 16; ++cp)
            lds_h[tid][cp] = pack_bf16x2(fmaxf(h2[2*cp], 0.f), fmaxf(h2[2*cp+1], 0.f));
    }
    lds_d[tid] = d;
    __syncthreads();

    if (p < N_EDGES) {
        int prevd = (tid == 0) ? lds_prev_d : lds_d[tid - 1];
        bool true_head = (prevd != d);
        bool is_head = (tid == 0) || true_head;
        if (is_head) {
            int idx = atomicAdd(&lds_cnt, 1);
            lds_heads[idx] = tid | (true_head ? 0x10000 : 0);
        }
    }
    __syncthreads();

    const int nseg = lds_cnt;
    const int next_d = lds_next_d;
    for (int w = tid; w < nseg * 16; w += 256) {
        int seg = w >> 4, cp = w & 15;
        int ent = lds_heads[seg];
        int h = ent & 0xFFFF;
        bool thead = (ent & 0x10000) != 0;
        int dd = lds_d[h];
        float s0 = 0.f, s1 = 0.f;
        int r = h;
        while (r < 256 && lds_d[r] == dd) {
            unsigned x = lds_h[r][cp];
            s0 += __uint_as_float(x << 16);
            s1 += __uint_as_float(x & 0xFFFF0000u);
            ++r;
        }
        bool end_complete = (r < 256) || (next_d != dd);
        float* dst = agg + (size_t)dd * 32 + 2 * cp;
        if (thead && end_complete) {
            *reinterpret_cast<float2*>(dst) = make_float2(s0, s1);
        } else {
            atomicAdd(dst + 0, s0);
            atomicAdd(dst + 1, s1);
        }
    }
}

// ---------------- node MLP (reads agg) -----------------------------------------

__global__ __launch_bounds__(256) void node_kernel(
    const float* __restrict__ u, const float* __restrict__ agg,
    const float* __restrict__ f_w1, const float* __restrict__ f_b1,
    const float* __restrict__ f_w2, const float* __restrict__ f_b2,
    const float* __restrict__ t_w, const float* __restrict__ t_b,
    float* __restrict__ out)
{
    int n = blockIdx.x * 256 + threadIdx.x;
    if (n >= U_NODES) return;
    float x[64];
    load32f(u   + (size_t)n * 32, x);
    load32f(agg + (size_t)n * 32, x + 32);
    float z1[64];
    #pragma unroll
    for (int j = 0; j < 64; ++j) z1[j] = f_b1[j];
    #pragma unroll
    for (int i = 0; i < 64; ++i) {
        #pragma unroll
        for (int j = 0; j < 64; ++j) z1[j] += x[i] * f_w1[i*64 + j];
    }
    #pragma unroll
    for (int j = 0; j < 64; ++j) z1[j] = fmaxf(z1[j], 0.f);
    float z2[32];
    #pragma unroll
    for (int k = 0; k < 32; ++k) z2[k] = f_b2[k];
    #pragma unroll
    for (int j = 0; j < 64; ++j) {
        #pragma unroll
        for (int k = 0; k < 32; ++k) z2[k] += z1[j] * f_w2[j*32 + k];
    }
    #pragma unroll
    for (int k = 0; k < 32; ++k) z2[k] = fmaxf(z2[k], 0.f);
    float o = t_b[0];
    #pragma unroll
    for (int k = 0; k < 32; ++k) o += z2[k] * t_w[k];
    out[n] = 1.f / (1.f + expf(-o));
}

// ---------------- last-resort atomic fallback -----------------------------------

__global__ __launch_bounds__(256) void edge_direct_kernel(
    const float* __restrict__ u, const float* __restrict__ v,
    const float* __restrict__ e_vals, const int* __restrict__ e_src,
    const int* __restrict__ e_dst, const float* __restrict__ g_w1,
    const float* __restrict__ g_b1, const float* __restrict__ g_w2,
    const float* __restrict__ g_b2, float* __restrict__ agg)
{
    int e = blockIdx.x * 256 + threadIdx.x;
    if (e >= N_EDGES) return;
    int d = e_dst[e];
    int s = e_src[e];
    float x[72];
    load32f(u + (size_t)d * 32, x);
    load32f(v + (size_t)s * 32, x + 32);
    load8f(e_vals + (size_t)e * 8, x + 64);
    float h1[64];
    #pragma unroll
    for (int j = 0; j < 64; ++j) h1[j] = g_b1[j];
    #pragma unroll
    for (int i = 0; i < 72; ++i) {
        #pragma unroll
        for (int j = 0; j < 64; ++j) h1[j] += x[i] * g_w1[i*64 + j];
    }
    #pragma unroll
    for (int j = 0; j < 64; ++j) h1[j] = fmaxf(h1[j], 0.f);
    float acc2[32];
    #pragma unroll
    for (int k = 0; k < 32; ++k) acc2[k] = g_b2[k];
    #pragma unroll
    for (int i = 0; i < 64; ++i) {
        #pragma unroll
        for (int k = 0; k < 32; ++k) acc2[k] += h1[i] * g_w2[i*32 + k];
    }
    float* aggp = agg + (size_t)d * 32;
    #pragma unroll
    for (int k = 0; k < 32; ++k) atomicAdd(aggp + k, fmaxf(acc2[k], 0.f));
}

// ---------------- launch -------------------------------------------------------

static inline size_t align256(size_t x) { return (x + 255) & ~(size_t)255; }

extern "C" void kernel_launch(void* const* d_in, const int* in_sizes, int n_in,
                              void* d_out, int out_size, void* d_ws, size_t ws_size,
                              hipStream_t stream) {
    const float* u      = (const float*)d_in[0];
    const float* v      = (const float*)d_in[1];
    const float* e_vals = (const float*)d_in[2];
    const int*   e_src  = (const int*)  d_in[3];
    const int*   e_dst  = (const int*)  d_in[4];
    const float* g_w1   = (const float*)d_in[5];
    const float* g_b1   = (const float*)d_in[6];
    const float* g_w2   = (const float*)d_in[7];
    const float* g_b2   = (const float*)d_in[8];
    const float* f_w1   = (const float*)d_in[9];
    const float* f_b1   = (const float*)d_in[10];
    const float* f_w2   = (const float*)d_in[11];
    const float* f_b2   = (const float*)d_in[12];
    const float* t_w    = (const float*)d_in[13];
    const float* t_b    = (const float*)d_in[14];
    float* out = (float*)d_out;

    char* wsc = (char*)d_ws;
    const int nChunks = (U_NODES + 255) / 256;                    // 391
    const int eBlocks = (N_EDGES + 255) / 256;

    const size_t degB  = align256((size_t)U_NODES * 4);
    const size_t offB  = align256((size_t)(U_NODES + 1) * 4);
    const size_t auxB  = align256((size_t)nChunks * 4);
    const size_t aggB  = align256((size_t)U_NODES * 32 * 4);      // 12.8 MB
    const size_t e4B   = align256((size_t)N_EDGES * 4);           // 8 MB
    const size_t epkB  = align256((size_t)N_EDGES * 32);          // 64 MB packed records
    const size_t bB    = align256((size_t)V_NODES * 64 * 4);      // 12.8 MB
    const size_t aB    = align256((size_t)U_NODES * 64 * 4);      // 25.6 MB

    size_t o = 0;
    size_t oDeg = o; o += degB;
    size_t oOff = o; o += offB;
    size_t oAux = o; o += auxB;
    size_t oAgg = o; o += aggB;
    size_t baseNeed = o;                                          // ~13.7 MB

    // MFMA-path layout
    size_t oEp = o;  o += epkB;
    size_t oBn = o;  o += bB;
    size_t needT2r = o + e4B;          // B + separate rank (~98.5 MB)
    size_t oAn = o;  o += aB;
    size_t needT1 = o;                 // ~116 MB ; rank aliases A (proj_u after permute)

    // fallback (round-4) layout
    size_t o3 = baseNeed;
    size_t oSeid = o3; o3 += e4B;
    size_t needT4 = o3 + e4B;          // <false,false> : rank after seid (~29.7 MB)
    size_t oB3 = o3;   o3 += bB;
    size_t oA3 = o3;   o3 += aB;
    size_t needT3 = o3;                // ~60 MB ; rank aliases A3

    int* deg   = (int*)(wsc + oDeg);
    int* off   = (int*)(wsc + oOff);
    int* aux   = (int*)(wsc + oAux);
    float* agg = (float*)(wsc + oAgg);

    if (ws_size >= needT2r) {
        const bool hasA = (ws_size >= needT1);
        unsigned* epk = (unsigned*)(wsc + oEp);
        float* B   = (float*)(wsc + oBn);
        float* A   = hasA ? (float*)(wsc + oAn) : nullptr;
        int* rank  = hasA ? (int*)A : (int*)(wsc + oAn);  // tier2: own 8MB past B

        hipMemsetAsync(deg, 0, (size_t)U_NODES * 4, stream);
        hipMemsetAsync(agg, 0, (size_t)U_NODES * 32 * 4, stream);

        rank_kernel<<<eBlocks, 256, 0, stream>>>(e_dst, deg, rank);
        scan_block_kernel<<<nChunks, 256, 0, stream>>>(deg, off, aux, U_NODES);
        scan_aux_kernel<<<1, 512, 0, stream>>>(aux, nChunks);
        scan_add_kernel<<<nChunks, 256, 0, stream>>>(off, aux, U_NODES);
        permute_pack_kernel<<<eBlocks, 256, 0, stream>>>(e_dst, e_src, rank, off,
                                                         e_vals, epk);
        proj_v_kernel<<<(V_NODES + 255) / 256, 256, 0, stream>>>(v, g_w1, g_b1, B);
        if (hasA) {
            proj_u_kernel<<<(U_NODES + 255) / 256, 256, 0, stream>>>(u, g_w1, A);
            edge_reg_kernel<<<eBlocks, 256, 0, stream>>>(
                A, B, epk, g_w1, g_w2, g_b2, agg);
        } else {
            edge_mfma_kernel<false><<<eBlocks, 256, 0, stream>>>(
                nullptr, B, u, epk, g_w1, g_w2, g_b2, agg);
        }
        node_kernel<<<(U_NODES + 255) / 256, 256, 0, stream>>>(
            u, agg, f_w1, f_b1, f_w2, f_b2, t_w, t_b, out);
    } else if (ws_size >= needT4) {
        const bool hasAB = (ws_size >= needT3);
        int* seid = (int*)(wsc + oSeid);
        float* B = hasAB ? (float*)(wsc + oB3) : nullptr;
        float* A = hasAB ? (float*)(wsc + oA3) : nullptr;
        int* rank = hasAB ? (int*)A : (int*)(wsc + oSeid + e4B);

        hipMemsetAsync(deg, 0, (size_t)U_NODES * 4, stream);
        hipMemsetAsync(agg, 0, (size_t)U_NODES * 32 * 4, stream);

        rank_kernel<<<eBlocks, 256, 0, stream>>>(e_dst, deg, rank);
        scan_block_kernel<<<nChunks, 256, 0, stream>>>(deg, off, aux, U_NODES);
        scan_aux_kernel<<<1, 512, 0, stream>>>(aux, nChunks);
        scan_add_kernel<<<nChunks, 256, 0, stream>>>(off, aux, U_NODES);
        scatter_kernel<<<eBlocks, 256, 0, stream>>>(e_dst, off, rank, seid);

        if (hasAB) {
            proj_v_kernel<<<(V_NODES + 255) / 256, 256, 0, stream>>>(v, g_w1, g_b1, B);
            proj_u_kernel<<<(U_NODES + 255) / 256, 256, 0, stream>>>(u, g_w1, A);
            edge_sorted_kernel<true, true><<<eBlocks, 256, 0, stream>>>(
                A, B, u, v, e_vals, e_src, e_dst, seid, g_w1, g_b1, g_w2, g_b2, agg);
        } else {
            edge_sorted_kernel<false, false><<<eBlocks, 256, 0, stream>>>(
                nullptr, nullptr, u, v, e_vals, e_src, e_dst, seid,
                g_w1, g_b1, g_w2, g_b2, agg);
        }
        node_kernel<<<(U_NODES + 255) / 256, 256, 0, stream>>>(
            u, agg, f_w1, f_b1, f_w2, f_b2, t_w, t_b, out);
    } else {
        float* agg0 = (float*)wsc;
        hipMemsetAsync(agg0, 0, (size_t)U_NODES * 32 * 4, stream);
        edge_direct_kernel<<<eBlocks, 256, 0, stream>>>(
            u, v, e_vals, e_src, e_dst, g_w1, g_b1, g_w2, g_b2, agg0);
        node_kernel<<<(U_NODES + 255) / 256, 256, 0, stream>>>(
            u, agg0, f_w1, f_b1, f_w2, f_b2, t_w, t_b, out);
    }
}

// Round 8
// 424.443 us; speedup vs baseline: 1.1670x; 1.1670x over previous
//
#include <hip/hip_runtime.h>
#include <cstdint>
#include <cstddef>

#define U_NODES 100000
#define V_NODES 50000
#define N_EDGES 2000000

// dims: F=32 (u), G=32 (v), H=8 (edge); g: 72->64->32 ; f: 64->64->32 ; tail 32->1
// g_w1 rows: [0,32) u-part, [32,64) v-part, [64,72) edge-val part.

typedef _Float16 f16x8 __attribute__((ext_vector_type(8)));
typedef _Float16 f16x2 __attribute__((ext_vector_type(2)));
typedef float    f32x4 __attribute__((ext_vector_type(4)));

__device__ __forceinline__ void load8f(const float* __restrict__ p, float* x) {
    const float4* p4 = reinterpret_cast<const float4*>(p);
    float4 a = p4[0], b = p4[1];
    x[0]=a.x; x[1]=a.y; x[2]=a.z; x[3]=a.w;
    x[4]=b.x; x[5]=b.y; x[6]=b.z; x[7]=b.w;
}

__device__ __forceinline__ void load32f(const float* __restrict__ p, float* x) {
    #pragma unroll
    for (int q = 0; q < 4; ++q) load8f(p + 8*q, x + 8*q);
}

__device__ __forceinline__ unsigned pack_bf16x2(float a, float b) {
    unsigned ua = __float_as_uint(a);
    ua = (ua + 0x7FFFu + ((ua >> 16) & 1u)) >> 16;
    unsigned ub = __float_as_uint(b);
    ub = (ub + 0x7FFFu + ((ub >> 16) & 1u)) & 0xFFFF0000u;
    return ua | ub;
}
__device__ __forceinline__ unsigned short bf16_1(float a) {
    unsigned ua = __float_as_uint(a);
    return (unsigned short)((ua + 0x7FFFu + ((ua >> 16) & 1u)) >> 16);
}

__device__ __forceinline__ unsigned pk16(float a, float b) {
    union { f16x2 h; unsigned u; } c;
    c.h[0] = (_Float16)a; c.h[1] = (_Float16)b;
    return c.u;
}
__device__ __forceinline__ float f16lo(unsigned w) {
    union { unsigned short u; _Float16 h; } c; c.u = (unsigned short)(w & 0xFFFFu);
    return (float)c.h;
}
__device__ __forceinline__ float f16hi(unsigned w) {
    union { unsigned short u; _Float16 h; } c; c.u = (unsigned short)(w >> 16);
    return (float)c.h;
}
__device__ __forceinline__ f16x8 as_f16x8(uint4 x) {
    union { uint4 u; f16x8 h; } c; c.u = x; return c.h;
}

// fdot2: acc += a.lo*b.lo + a.hi*b.hi (f16 inputs, f32 accum)
__device__ __forceinline__ float fdot2f(unsigned a, unsigned b, float c) {
#if defined(__has_builtin) && __has_builtin(__builtin_amdgcn_fdot2)
    union { unsigned u; f16x2 h; } ca, cb; ca.u = a; cb.u = b;
    return __builtin_amdgcn_fdot2(ca.h, cb.h, c, false);
#else
    return c + f16lo(a)*f16lo(b) + f16hi(a)*f16hi(b);
#endif
}

// ---------------- pre-projection (A = u@W1u ; B = v@W1v + b1) ------------------

__global__ __launch_bounds__(256) void proj_u_kernel(
    const float* __restrict__ u, const float* __restrict__ g_w1,
    float* __restrict__ A)
{
    int n = blockIdx.x * 256 + threadIdx.x;
    if (n >= U_NODES) return;
    float x[32];
    load32f(u + (size_t)n * 32, x);
    float acc[64];
    #pragma unroll
    for (int j = 0; j < 64; ++j) acc[j] = 0.f;
    #pragma unroll
    for (int i = 0; i < 32; ++i) {
        #pragma unroll
        for (int j = 0; j < 64; ++j) acc[j] += x[i] * g_w1[i*64 + j];
    }
    float4* Ap = reinterpret_cast<float4*>(A + (size_t)n * 64);
    #pragma unroll
    for (int q = 0; q < 16; ++q)
        Ap[q] = make_float4(acc[4*q], acc[4*q+1], acc[4*q+2], acc[4*q+3]);
}

__global__ __launch_bounds__(256) void proj_v_kernel(
    const float* __restrict__ v, const float* __restrict__ g_w1,
    const float* __restrict__ g_b1, float* __restrict__ B)
{
    int n = blockIdx.x * 256 + threadIdx.x;
    if (n >= V_NODES) return;
    float x[32];
    load32f(v + (size_t)n * 32, x);
    float acc[64];
    #pragma unroll
    for (int j = 0; j < 64; ++j) acc[j] = g_b1[j];
    #pragma unroll
    for (int i = 0; i < 32; ++i) {
        #pragma unroll
        for (int j = 0; j < 64; ++j) acc[j] += x[i] * g_w1[(32+i)*64 + j];
    }
    float4* Bp = reinterpret_cast<float4*>(B + (size_t)n * 64);
    #pragma unroll
    for (int q = 0; q < 16; ++q)
        Bp[q] = make_float4(acc[4*q], acc[4*q+1], acc[4*q+2], acc[4*q+3]);
}

// ---------------- CSR build ----------------------------------------------------

__global__ __launch_bounds__(256) void rank_kernel(
    const int* __restrict__ e_dst, int* __restrict__ deg, int* __restrict__ rank)
{
    int e = blockIdx.x * 256 + threadIdx.x;
    if (e >= N_EDGES) return;
    rank[e] = atomicAdd(&deg[e_dst[e]], 1);
}

__global__ __launch_bounds__(256) void scan_block_kernel(
    const int* __restrict__ deg, int* __restrict__ off, int* __restrict__ aux, int n)
{
    __shared__ int s[256];
    int tid = threadIdx.x;
    int i = blockIdx.x * 256 + tid;
    int x = (i < n) ? deg[i] : 0;
    s[tid] = x;
    __syncthreads();
    #pragma unroll
    for (int o = 1; o < 256; o <<= 1) {
        int t = (tid >= o) ? s[tid - o] : 0;
        __syncthreads();
        s[tid] += t;
        __syncthreads();
    }
    if (i < n) off[i + 1] = s[tid];
    if (tid == 255) aux[blockIdx.x] = s[255];
}

__global__ __launch_bounds__(512) void scan_aux_kernel(int* __restrict__ aux, int nA)
{
    __shared__ int s[512];
    int tid = threadIdx.x;
    int x = (tid < nA) ? aux[tid] : 0;
    s[tid] = x;
    __syncthreads();
    #pragma unroll
    for (int o = 1; o < 512; o <<= 1) {
        int t = (tid >= o) ? s[tid - o] : 0;
        __syncthreads();
        s[tid] += t;
        __syncthreads();
    }
    if (tid < nA) aux[tid] = s[tid] - x;  // exclusive
}

__global__ __launch_bounds__(256) void scan_add_kernel(
    int* __restrict__ off, const int* __restrict__ aux, int n)
{
    int i = blockIdx.x * 256 + threadIdx.x;
    if (i == 0) off[0] = 0;
    if (i < n) off[i + 1] += aux[i >> 8];
}

__global__ __launch_bounds__(256) void scatter_kernel(
    const int* __restrict__ e_dst, const int* __restrict__ off,
    const int* __restrict__ rank, int* __restrict__ sorted_eid)
{
    int e = blockIdx.x * 256 + threadIdx.x;
    if (e >= N_EDGES) return;
    int d = e_dst[e];
    sorted_eid[off[d] + rank[e]] = e;
}

// packed 32B edge record: [d, s, ev16 x4, pad x2] -> ONE sector touch per edge
__global__ __launch_bounds__(256) void permute_pack_kernel(
    const int* __restrict__ e_dst, const int* __restrict__ e_src,
    const int* __restrict__ rank, const int* __restrict__ off,
    const float* __restrict__ e_vals, unsigned* __restrict__ epk)
{
    int e = blockIdx.x * 256 + threadIdx.x;
    if (e >= N_EDGES) return;
    int d = e_dst[e];
    int pos = off[d] + rank[e];
    float ev[8];
    load8f(e_vals + (size_t)e * 8, ev);
    uint4 w0;
    w0.x = (unsigned)d;
    w0.y = (unsigned)e_src[e];
    w0.z = pk16(ev[0], ev[1]);
    w0.w = pk16(ev[2], ev[3]);
    uint2 w1;
    w1.x = pk16(ev[4], ev[5]);
    w1.y = pk16(ev[6], ev[7]);
    unsigned* dst = epk + (size_t)pos * 8;
    *reinterpret_cast<uint4*>(dst)     = w0;
    *reinterpret_cast<uint2*>(dst + 4) = w1;
}

// ---- edge kernel v8: fragment-direct h1 (registers) + MFMA W2
//      + classic block-wide segmented reduce over bf16-packed h2 (stride 17) ----
// Requires A (dest-proj) and B (src-proj incl bias) precomputed.

__global__ __launch_bounds__(256) void edge_frag_kernel(
    const float* __restrict__ A, const float* __restrict__ B,
    const unsigned* __restrict__ epk,
    const float* __restrict__ g_w1, const float* __restrict__ g_w2,
    const float* __restrict__ g_b2, float* __restrict__ agg)
{
    __shared__ unsigned s_w2[32 * 33];                  // f16x2 W2 [kp][n]
    __shared__ __align__(16) unsigned s_w1e[4 * 64];    // f16x2 W1e row-pairs
    __shared__ unsigned s_h2[256 * 17];                 // bf16x2 h2 [edge][cp]
    __shared__ int s_d[256];
    __shared__ int s_heads[256];                        // tid | (true_head<<16)
    __shared__ int s_cnt, s_prevd, s_nextd;

    const int tid = threadIdx.x;
    const long bP = (long)blockIdx.x * 256;

    // stage W2 as f16 pairs
    #pragma unroll
    for (int i = 0; i < 4; ++i) {
        int idx = tid + i * 256;
        int kp = idx >> 5, n = idx & 31;
        s_w2[kp * 33 + n] = pk16(g_w2[(2*kp)*32 + n], g_w2[(2*kp+1)*32 + n]);
    }
    // stage W1e row-pairs (rows 64..71 of g_w1)
    {
        int i2 = tid >> 6, c = tid & 63;
        s_w1e[i2 * 64 + c] = pk16(g_w1[(64 + 2*i2)*64 + c], g_w1[(64 + 2*i2 + 1)*64 + c]);
    }
    if (tid == 0) {
        s_cnt = 0;
        s_prevd = (bP > 0) ? (int)epk[(size_t)(bP - 1) * 8] : -2;
        s_nextd = (bP + 256 < (long)N_EDGES) ? (int)epk[(size_t)(bP + 256) * 8] : -2;
    }

    const int wv   = tid >> 6;
    const int lane = tid & 63;
    const int lm   = lane & 15;
    const int lg   = lane >> 4;
    const long wP  = bP + wv * 64;

    // load my 4 edges' records (fragment layout); lg==0 publishes d to s_d
    int dM[4], sM[4];
    unsigned evp[4][4];
    #pragma unroll
    for (int mt = 0; mt < 4; ++mt) {
        long pe = wP + mt*16 + lm;
        if (pe < (long)N_EDGES) {
            const unsigned* ep = epk + (size_t)pe * 8;
            uint4 w0 = *reinterpret_cast<const uint4*>(ep);
            uint2 w1 = *reinterpret_cast<const uint2*>(ep + 4);
            dM[mt] = (int)w0.x; sM[mt] = (int)w0.y;
            evp[mt][0] = w0.z; evp[mt][1] = w0.w; evp[mt][2] = w1.x; evp[mt][3] = w1.y;
        } else {
            dM[mt] = -1; sM[mt] = 0;
            evp[mt][0] = evp[mt][1] = evp[mt][2] = evp[mt][3] = 0;
        }
        if (lg == 0) s_d[wv*64 + mt*16 + lm] = dM[mt];
    }
    __syncthreads();   // barrier 1: s_d + W staging complete

    // head marking (block-wide, overlaps with compute below)
    if (bP + tid < (long)N_EDGES) {
        int d_me  = s_d[tid];
        int prevd = (tid == 0) ? s_prevd : s_d[tid - 1];
        bool true_head = (prevd != d_me);
        bool is_head = (tid == 0) || true_head;
        if (is_head) {
            int idx = atomicAdd(&s_cnt, 1);
            s_heads[idx] = tid | (true_head ? 0x10000 : 0);
        }
    }

    // ---- h1 in MFMA A-fragment registers ----
    uint4 afr[4][2];
    #pragma unroll
    for (int kt = 0; kt < 2; ++kt) {
        float acc[4][8];
        #pragma unroll
        for (int mt = 0; mt < 4; ++mt) {
            if (dM[mt] >= 0) {
                const float4* Ap = reinterpret_cast<const float4*>(A + (size_t)dM[mt]*64 + kt*32 + lg*8);
                const float4* Bp = reinterpret_cast<const float4*>(B + (size_t)sM[mt]*64 + kt*32 + lg*8);
                float4 a0 = Ap[0], a1 = Ap[1], b0 = Bp[0], b1 = Bp[1];
                acc[mt][0] = a0.x + b0.x; acc[mt][1] = a0.y + b0.y;
                acc[mt][2] = a0.z + b0.z; acc[mt][3] = a0.w + b0.w;
                acc[mt][4] = a1.x + b1.x; acc[mt][5] = a1.y + b1.y;
                acc[mt][6] = a1.z + b1.z; acc[mt][7] = a1.w + b1.w;
            } else {
                #pragma unroll
                for (int j = 0; j < 8; ++j) acc[mt][j] = 0.f;
            }
        }
        #pragma unroll
        for (int i2 = 0; i2 < 4; ++i2) {
            uint4 wA = *reinterpret_cast<const uint4*>(&s_w1e[i2*64 + kt*32 + lg*8]);
            uint4 wB = *reinterpret_cast<const uint4*>(&s_w1e[i2*64 + kt*32 + lg*8 + 4]);
            #pragma unroll
            for (int mt = 0; mt < 4; ++mt) {
                unsigned e2 = evp[mt][i2];
                acc[mt][0] = fdot2f(e2, wA.x, acc[mt][0]);
                acc[mt][1] = fdot2f(e2, wA.y, acc[mt][1]);
                acc[mt][2] = fdot2f(e2, wA.z, acc[mt][2]);
                acc[mt][3] = fdot2f(e2, wA.w, acc[mt][3]);
                acc[mt][4] = fdot2f(e2, wB.x, acc[mt][4]);
                acc[mt][5] = fdot2f(e2, wB.y, acc[mt][5]);
                acc[mt][6] = fdot2f(e2, wB.z, acc[mt][6]);
                acc[mt][7] = fdot2f(e2, wB.w, acc[mt][7]);
            }
        }
        #pragma unroll
        for (int mt = 0; mt < 4; ++mt) {
            uint4 w;
            w.x = pk16(fmaxf(acc[mt][0], 0.f), fmaxf(acc[mt][1], 0.f));
            w.y = pk16(fmaxf(acc[mt][2], 0.f), fmaxf(acc[mt][3], 0.f));
            w.z = pk16(fmaxf(acc[mt][4], 0.f), fmaxf(acc[mt][5], 0.f));
            w.w = pk16(fmaxf(acc[mt][6], 0.f), fmaxf(acc[mt][7], 0.f));
            afr[mt][kt] = w;
        }
    }

    // ---- MFMA: [64 edges x 64] @ [64 x 32] ----
    f32x4 mac[4][2];
    #pragma unroll
    for (int mt = 0; mt < 4; ++mt) {
        #pragma unroll
        for (int nt = 0; nt < 2; ++nt) {
            mac[mt][nt][0] = 0.f; mac[mt][nt][1] = 0.f;
            mac[mt][nt][2] = 0.f; mac[mt][nt][3] = 0.f;
        }
    }
    #pragma unroll
    for (int kt = 0; kt < 2; ++kt) {
        uint4 bf0, bf1;
        int kp = kt*16 + lg*4;
        bf0.x = s_w2[(kp+0)*33 + lm];      bf1.x = s_w2[(kp+0)*33 + 16 + lm];
        bf0.y = s_w2[(kp+1)*33 + lm];      bf1.y = s_w2[(kp+1)*33 + 16 + lm];
        bf0.z = s_w2[(kp+2)*33 + lm];      bf1.z = s_w2[(kp+2)*33 + 16 + lm];
        bf0.w = s_w2[(kp+3)*33 + lm];      bf1.w = s_w2[(kp+3)*33 + 16 + lm];
        f16x8 b0 = as_f16x8(bf0), b1 = as_f16x8(bf1);
        #pragma unroll
        for (int mt = 0; mt < 4; ++mt) {
            f16x8 a = as_f16x8(afr[mt][kt]);
            mac[mt][0] = __builtin_amdgcn_mfma_f32_16x16x32_f16(a, b0, mac[mt][0], 0, 0, 0);
            mac[mt][1] = __builtin_amdgcn_mfma_f32_16x16x32_f16(a, b1, mac[mt][1], 0, 0, 0);
        }
    }

    // ---- write h2 = relu(mac + b2) as packed bf16 to LDS ----
    // D layout: edge row = lg*4 + r (within 16-tile mt), channel col = lm / 16+lm
    float b2a = g_b2[lm], b2b = g_b2[16 + lm];
    unsigned short* h2s = reinterpret_cast<unsigned short*>(s_h2);
    #pragma unroll
    for (int mt = 0; mt < 4; ++mt) {
        #pragma unroll
        for (int r = 0; r < 4; ++r) {
            int edge = wv*64 + mt*16 + lg*4 + r;
            h2s[edge*34 + lm]      = bf16_1(fmaxf(mac[mt][0][r] + b2a, 0.f));
            h2s[edge*34 + 16 + lm] = bf16_1(fmaxf(mac[mt][1][r] + b2b, 0.f));
        }
    }
    __syncthreads();   // barrier 2: h2 + heads ready

    // ---- classic segmented reduce (16 channel-pairs per segment) ----
    const int nseg = s_cnt;
    const int next_d = s_nextd;
    for (int w = tid; w < nseg * 16; w += 256) {
        int seg = w >> 4, cp = w & 15;
        int ent = s_heads[seg];
        int h = ent & 0xFFFF;
        bool thead = (ent & 0x10000) != 0;
        int dd = s_d[h];
        float s0 = 0.f, s1 = 0.f;
        int r = h;
        while (r < 256 && s_d[r] == dd) {
            unsigned x = s_h2[r*17 + cp];
            s0 += __uint_as_float(x << 16);
            s1 += __uint_as_float(x & 0xFFFF0000u);
            ++r;
        }
        bool end_complete = (r < 256) || (next_d != dd);
        float* dst = agg + (size_t)dd * 32 + 2 * cp;
        if (thead && end_complete) {
            *reinterpret_cast<float2*>(dst) = make_float2(s0, s1);  // sole writer
        } else {
            atomicAdd(dst + 0, s0);
            atomicAdd(dst + 1, s1);
        }
    }
}

// ------- fallback tier-2: round-6 kernel (B precomputed, u-part on the fly) ----

template <bool HAS_A>
__global__ __launch_bounds__(256) void edge_mfma_kernel(
    const float* __restrict__ A, const float* __restrict__ B,
    const float* __restrict__ u, const unsigned* __restrict__ epk,
    const float* __restrict__ g_w1, const float* __restrict__ g_w2,
    const float* __restrict__ g_b2, float* __restrict__ agg)
{
    __shared__ unsigned s_h1[256 * 36];
    __shared__ unsigned s_w2[32 * 33];
    __shared__ int s_d[256];
    __shared__ int s_heads[256];
    __shared__ int s_cnt, s_prevd, s_nextd;

    const int tid = threadIdx.x;
    const long p = (long)blockIdx.x * 256 + tid;

    if (tid == 0) {
        s_cnt = 0;
        long pprev = (long)blockIdx.x * 256 - 1;
        s_prevd = (pprev < 0) ? -2 : (int)epk[(size_t)pprev * 8];
        long pnext = (long)blockIdx.x * 256 + 256;
        s_nextd = (pnext >= N_EDGES) ? -2 : (int)epk[(size_t)pnext * 8];
    }
    #pragma unroll
    for (int i = 0; i < 4; ++i) {
        int idx = tid + i * 256;
        int kp = idx >> 5, n = idx & 31;
        s_w2[kp * 33 + n] = pk16(g_w2[(2*kp)*32 + n], g_w2[(2*kp+1)*32 + n]);
    }

    int d = -1;
    if (p < N_EDGES) {
        const unsigned* ep = epk + (size_t)p * 8;
        uint4 w0 = *reinterpret_cast<const uint4*>(ep);
        uint2 w1 = *reinterpret_cast<const uint2*>(ep + 4);
        d = (int)w0.x;
        int s = (int)w0.y;

        float h1[64];
        if constexpr (HAS_A) {
            const float4* Ap = reinterpret_cast<const float4*>(A + (size_t)d * 64);
            #pragma unroll
            for (int q = 0; q < 16; ++q) {
                float4 a = Ap[q];
                h1[4*q+0] = a.x; h1[4*q+1] = a.y; h1[4*q+2] = a.z; h1[4*q+3] = a.w;
            }
        } else {
            #pragma unroll
            for (int j = 0; j < 64; ++j) h1[j] = 0.f;
            float x[32];
            load32f(u + (size_t)d * 32, x);
            #pragma unroll
            for (int i = 0; i < 32; ++i) {
                #pragma unroll
                for (int j = 0; j < 64; ++j) h1[j] += x[i] * g_w1[i*64 + j];
            }
        }
        {
            const float4* Bp = reinterpret_cast<const float4*>(B + (size_t)s * 64);
            #pragma unroll
            for (int q = 0; q < 16; ++q) {
                float4 b = Bp[q];
                h1[4*q+0] += b.x; h1[4*q+1] += b.y; h1[4*q+2] += b.z; h1[4*q+3] += b.w;
            }
        }
        float ev[8];
        ev[0]=f16lo(w0.z); ev[1]=f16hi(w0.z); ev[2]=f16lo(w0.w); ev[3]=f16hi(w0.w);
        ev[4]=f16lo(w1.x); ev[5]=f16hi(w1.x); ev[6]=f16lo(w1.y); ev[7]=f16hi(w1.y);
        #pragma unroll
        for (int i = 0; i < 8; ++i) {
            #pragma unroll
            for (int j = 0; j < 64; ++j) h1[j] += ev[i] * g_w1[(64+i)*64 + j];
        }
        #pragma unroll
        for (int j = 0; j < 64; ++j) h1[j] = fmaxf(h1[j], 0.f);

        #pragma unroll
        for (int q = 0; q < 8; ++q) {
            uint4 w;
            w.x = pk16(h1[8*q+0], h1[8*q+1]);
            w.y = pk16(h1[8*q+2], h1[8*q+3]);
            w.z = pk16(h1[8*q+4], h1[8*q+5]);
            w.w = pk16(h1[8*q+6], h1[8*q+7]);
            *reinterpret_cast<uint4*>(&s_h1[tid*36 + 4*q]) = w;
        }
    }
    s_d[tid] = d;
    __syncthreads();

    if (p < N_EDGES) {
        int prevd = (tid == 0) ? s_prevd : s_d[tid - 1];
        bool true_head = (prevd != d);
        bool is_head = (tid == 0) || true_head;
        if (is_head) {
            int idx = atomicAdd(&s_cnt, 1);
            s_heads[idx] = tid | (true_head ? 0x10000 : 0);
        }
    }

    const int lane = tid & 63;
    const int wb   = (tid >> 6) * 64;
    const int lg   = lane >> 4;
    const int lm   = lane & 15;

    f32x4 acc[4][2];
    #pragma unroll
    for (int mt = 0; mt < 4; ++mt) {
        #pragma unroll
        for (int nt = 0; nt < 2; ++nt) {
            acc[mt][nt][0] = 0.f; acc[mt][nt][1] = 0.f;
            acc[mt][nt][2] = 0.f; acc[mt][nt][3] = 0.f;
        }
    }
    #pragma unroll
    for (int kt = 0; kt < 2; ++kt) {
        uint4 bf0, bf1;
        int kp = kt*16 + lg*4;
        bf0.x = s_w2[(kp+0)*33 + lm];      bf1.x = s_w2[(kp+0)*33 + 16 + lm];
        bf0.y = s_w2[(kp+1)*33 + lm];      bf1.y = s_w2[(kp+1)*33 + 16 + lm];
        bf0.z = s_w2[(kp+2)*33 + lm];      bf1.z = s_w2[(kp+2)*33 + 16 + lm];
        bf0.w = s_w2[(kp+3)*33 + lm];      bf1.w = s_w2[(kp+3)*33 + 16 + lm];
        f16x8 b0 = as_f16x8(bf0), b1 = as_f16x8(bf1);
        #pragma unroll
        for (int mt = 0; mt < 4; ++mt) {
            uint4 av = *reinterpret_cast<const uint4*>(
                &s_h1[(wb + mt*16 + lm)*36 + kt*16 + lg*4]);
            f16x8 a = as_f16x8(av);
            acc[mt][0] = __builtin_amdgcn_mfma_f32_16x16x32_f16(a, b0, acc[mt][0], 0, 0, 0);
            acc[mt][1] = __builtin_amdgcn_mfma_f32_16x16x32_f16(a, b1, acc[mt][1], 0, 0, 0);
        }
    }
    float b2a = g_b2[lm];
    float b2b = g_b2[16 + lm];
    __syncthreads();

    float* h2f = reinterpret_cast<float*>(s_h1);
    #pragma unroll
    for (int mt = 0; mt < 4; ++mt) {
        #pragma unroll
        for (int r = 0; r < 4; ++r) {
            int row = wb + mt*16 + lg*4 + r;
            h2f[row*36 + lm]      = fmaxf(acc[mt][0][r] + b2a, 0.f);
            h2f[row*36 + 16 + lm] = fmaxf(acc[mt][1][r] + b2b, 0.f);
        }
    }
    __syncthreads();

    const int nseg = s_cnt;
    const int next_d = s_nextd;
    for (int w = tid; w < nseg * 16; w += 256) {
        int seg = w >> 4, cp = w & 15;
        int ent = s_heads[seg];
        int h = ent & 0xFFFF;
        bool thead = (ent & 0x10000) != 0;
        int dd = s_d[h];
        float s0 = 0.f, s1 = 0.f;
        int r = h;
        while (r < 256 && s_d[r] == dd) {
            s0 += h2f[r*36 + 2*cp];
            s1 += h2f[r*36 + 2*cp + 1];
            ++r;
        }
        bool end_complete = (r < 256) || (next_d != dd);
        float* dst = agg + (size_t)dd * 32 + 2 * cp;
        if (thead && end_complete) {
            *reinterpret_cast<float2*>(dst) = make_float2(s0, s1);
        } else {
            atomicAdd(dst + 0, s0);
            atomicAdd(dst + 1, s1);
        }
    }
}

// ------- fallback: edge MLP via seid gathers (round-4 proven path) --------------

template <bool HAS_A, bool HAS_B>
__global__ __launch_bounds__(256) void edge_sorted_kernel(
    const float* __restrict__ A, const float* __restrict__ B,
    const float* __restrict__ u, const float* __restrict__ v,
    const float* __restrict__ e_vals, const int* __restrict__ e_src,
    const int* __restrict__ e_dst, const int* __restrict__ seid,
    const float* __restrict__ g_w1, const float* __restrict__ g_b1,
    const float* __restrict__ g_w2, const float* __restrict__ g_b2,
    float* __restrict__ agg)
{
    __shared__ unsigned lds_h[256][17];
    __shared__ int lds_d[256];
    __shared__ int lds_heads[256];
    __shared__ int lds_cnt;
    __shared__ int lds_prev_d, lds_next_d;

    const int tid = threadIdx.x;
    const long p = (long)blockIdx.x * 256 + tid;

    if (tid == 0) {
        lds_cnt = 0;
        long pprev = (long)blockIdx.x * 256 - 1;
        lds_prev_d = (pprev < 0) ? -2 : e_dst[seid[pprev]];
        long pnext = (long)blockIdx.x * 256 + 256;
        lds_next_d = (pnext >= N_EDGES) ? -2 : e_dst[seid[pnext]];
    }

    int d = -1;
    if (p < N_EDGES) {
        int eid = seid[p];
        d = e_dst[eid];
        int s = e_src[eid];

        float h1[64];
        if constexpr (HAS_A) {
            const float4* Ap = reinterpret_cast<const float4*>(A + (size_t)d * 64);
            #pragma unroll
            for (int q = 0; q < 16; ++q) {
                float4 a = Ap[q];
                h1[4*q+0] = a.x; h1[4*q+1] = a.y; h1[4*q+2] = a.z; h1[4*q+3] = a.w;
            }
        } else {
            #pragma unroll
            for (int j = 0; j < 64; ++j) h1[j] = 0.f;
            float x[32];
            load32f(u + (size_t)d * 32, x);
            #pragma unroll
            for (int i = 0; i < 32; ++i) {
                #pragma unroll
                for (int j = 0; j < 64; ++j) h1[j] += x[i] * g_w1[i*64 + j];
            }
        }
        if constexpr (HAS_B) {
            const float4* Bp = reinterpret_cast<const float4*>(B + (size_t)s * 64);
            #pragma unroll
            for (int q = 0; q < 16; ++q) {
                float4 b = Bp[q];
                h1[4*q+0] += b.x; h1[4*q+1] += b.y; h1[4*q+2] += b.z; h1[4*q+3] += b.w;
            }
        } else {
            #pragma unroll
            for (int j = 0; j < 64; ++j) h1[j] += g_b1[j];
            float x[32];
            load32f(v + (size_t)s * 32, x);
            #pragma unroll
            for (int i = 0; i < 32; ++i) {
                #pragma unroll
                for (int j = 0; j < 64; ++j) h1[j] += x[i] * g_w1[(32+i)*64 + j];
            }
        }
        float ev[8];
        load8f(e_vals + (size_t)eid * 8, ev);
        #pragma unroll
        for (int i = 0; i < 8; ++i) {
            #pragma unroll
            for (int j = 0; j < 64; ++j) h1[j] += ev[i] * g_w1[(64+i)*64 + j];
        }
        #pragma unroll
        for (int j = 0; j < 64; ++j) h1[j] = fmaxf(h1[j], 0.f);

        float h2[32];
        #pragma unroll
        for (int k = 0; k < 32; ++k) h2[k] = g_b2[k];
        #pragma unroll
        for (int i = 0; i < 64; ++i) {
            #pragma unroll
            for (int k = 0; k < 32; ++k) h2[k] += h1[i] * g_w2[i*32 + k];
        }
        #pragma unroll
        for (int cp = 0; cp < 16; ++cp)
            lds_h[tid][cp] = pack_bf16x2(fmaxf(h2[2*cp], 0.f), fmaxf(h2[2*cp+1], 0.f));
    }
    lds_d[tid] = d;
    __syncthreads();

    if (p < N_EDGES) {
        int prevd = (tid == 0) ? lds_prev_d : lds_d[tid - 1];
        bool true_head = (prevd != d);
        bool is_head = (tid == 0) || true_head;
        if (is_head) {
            int idx = atomicAdd(&lds_cnt, 1);
            lds_heads[idx] = tid | (true_head ? 0x10000 : 0);
        }
    }
    __syncthreads();

    const int nseg = lds_cnt;
    const int next_d = lds_next_d;
    for (int w = tid; w < nseg * 16; w += 256) {
        int seg = w >> 4, cp = w & 15;
        int ent = lds_heads[seg];
        int h = ent & 0xFFFF;
        bool thead = (ent & 0x10000) != 0;
        int dd = lds_d[h];
        float s0 = 0.f, s1 = 0.f;
        int r = h;
        while (r < 256 && lds_d[r] == dd) {
            unsigned x = lds_h[r][cp];
            s0 += __uint_as_float(x << 16);
            s1 += __uint_as_float(x & 0xFFFF0000u);
            ++r;
        }
        bool end_complete = (r < 256) || (next_d != dd);
        float* dst = agg + (size_t)dd * 32 + 2 * cp;
        if (thead && end_complete) {
            *reinterpret_cast<float2*>(dst) = make_float2(s0, s1);
        } else {
            atomicAdd(dst + 0, s0);
            atomicAdd(dst + 1, s1);
        }
    }
}

// ---------------- node MLP (reads agg) -----------------------------------------

__global__ __launch_bounds__(256) void node_kernel(
    const float* __restrict__ u, const float* __restrict__ agg,
    const float* __restrict__ f_w1, const float* __restrict__ f_b1,
    const float* __restrict__ f_w2, const float* __restrict__ f_b2,
    const float* __restrict__ t_w, const float* __restrict__ t_b,
    float* __restrict__ out)
{
    int n = blockIdx.x * 256 + threadIdx.x;
    if (n >= U_NODES) return;
    float x[64];
    load32f(u   + (size_t)n * 32, x);
    load32f(agg + (size_t)n * 32, x + 32);
    float z1[64];
    #pragma unroll
    for (int j = 0; j < 64; ++j) z1[j] = f_b1[j];
    #pragma unroll
    for (int i = 0; i < 64; ++i) {
        #pragma unroll
        for (int j = 0; j < 64; ++j) z1[j] += x[i] * f_w1[i*64 + j];
    }
    #pragma unroll
    for (int j = 0; j < 64; ++j) z1[j] = fmaxf(z1[j], 0.f);
    float z2[32];
    #pragma unroll
    for (int k = 0; k < 32; ++k) z2[k] = f_b2[k];
    #pragma unroll
    for (int j = 0; j < 64; ++j) {
        #pragma unroll
        for (int k = 0; k < 32; ++k) z2[k] += z1[j] * f_w2[j*32 + k];
    }
    #pragma unroll
    for (int k = 0; k < 32; ++k) z2[k] = fmaxf(z2[k], 0.f);
    float o = t_b[0];
    #pragma unroll
    for (int k = 0; k < 32; ++k) o += z2[k] * t_w[k];
    out[n] = 1.f / (1.f + expf(-o));
}

// ---------------- last-resort atomic fallback -----------------------------------

__global__ __launch_bounds__(256) void edge_direct_kernel(
    const float* __restrict__ u, const float* __restrict__ v,
    const float* __restrict__ e_vals, const int* __restrict__ e_src,
    const int* __restrict__ e_dst, const float* __restrict__ g_w1,
    const float* __restrict__ g_b1, const float* __restrict__ g_w2,
    const float* __restrict__ g_b2, float* __restrict__ agg)
{
    int e = blockIdx.x * 256 + threadIdx.x;
    if (e >= N_EDGES) return;
    int d = e_dst[e];
    int s = e_src[e];
    float x[72];
    load32f(u + (size_t)d * 32, x);
    load32f(v + (size_t)s * 32, x + 32);
    load8f(e_vals + (size_t)e * 8, x + 64);
    float h1[64];
    #pragma unroll
    for (int j = 0; j < 64; ++j) h1[j] = g_b1[j];
    #pragma unroll
    for (int i = 0; i < 72; ++i) {
        #pragma unroll
        for (int j = 0; j < 64; ++j) h1[j] += x[i] * g_w1[i*64 + j];
    }
    #pragma unroll
    for (int j = 0; j < 64; ++j) h1[j] = fmaxf(h1[j], 0.f);
    float acc2[32];
    #pragma unroll
    for (int k = 0; k < 32; ++k) acc2[k] = g_b2[k];
    #pragma unroll
    for (int i = 0; i < 64; ++i) {
        #pragma unroll
        for (int k = 0; k < 32; ++k) acc2[k] += h1[i] * g_w2[i*32 + k];
    }
    float* aggp = agg + (size_t)d * 32;
    #pragma unroll
    for (int k = 0; k < 32; ++k) atomicAdd(aggp + k, fmaxf(acc2[k], 0.f));
}

// ---------------- launch -------------------------------------------------------

static inline size_t align256(size_t x) { return (x + 255) & ~(size_t)255; }

extern "C" void kernel_launch(void* const* d_in, const int* in_sizes, int n_in,
                              void* d_out, int out_size, void* d_ws, size_t ws_size,
                              hipStream_t stream) {
    const float* u      = (const float*)d_in[0];
    const float* v      = (const float*)d_in[1];
    const float* e_vals = (const float*)d_in[2];
    const int*   e_src  = (const int*)  d_in[3];
    const int*   e_dst  = (const int*)  d_in[4];
    const float* g_w1   = (const float*)d_in[5];
    const float* g_b1   = (const float*)d_in[6];
    const float* g_w2   = (const float*)d_in[7];
    const float* g_b2   = (const float*)d_in[8];
    const float* f_w1   = (const float*)d_in[9];
    const float* f_b1   = (const float*)d_in[10];
    const float* f_w2   = (const float*)d_in[11];
    const float* f_b2   = (const float*)d_in[12];
    const float* t_w    = (const float*)d_in[13];
    const float* t_b    = (const float*)d_in[14];
    float* out = (float*)d_out;

    char* wsc = (char*)d_ws;
    const int nChunks = (U_NODES + 255) / 256;                    // 391
    const int eBlocks = (N_EDGES + 255) / 256;

    const size_t degB  = align256((size_t)U_NODES * 4);
    const size_t offB  = align256((size_t)(U_NODES + 1) * 4);
    const size_t auxB  = align256((size_t)nChunks * 4);
    const size_t aggB  = align256((size_t)U_NODES * 32 * 4);      // 12.8 MB
    const size_t e4B   = align256((size_t)N_EDGES * 4);           // 8 MB
    const size_t epkB  = align256((size_t)N_EDGES * 32);          // 64 MB packed records
    const size_t bB    = align256((size_t)V_NODES * 64 * 4);      // 12.8 MB
    const size_t aB    = align256((size_t)U_NODES * 64 * 4);      // 25.6 MB

    size_t o = 0;
    size_t oDeg = o; o += degB;
    size_t oOff = o; o += offB;
    size_t oAux = o; o += auxB;
    size_t oAgg = o; o += aggB;
    size_t baseNeed = o;                                          // ~13.7 MB

    // MFMA-path layout
    size_t oEp = o;  o += epkB;
    size_t oBn = o;  o += bB;
    size_t needT2r = o + e4B;          // B + separate rank (~98.5 MB)
    size_t oAn = o;  o += aB;
    size_t needT1 = o;                 // ~116 MB ; rank aliases A (proj_u after permute)

    // fallback (round-4) layout
    size_t o3 = baseNeed;
    size_t oSeid = o3; o3 += e4B;
    size_t needT4 = o3 + e4B;          // <false,false> : rank after seid (~29.7 MB)
    size_t oB3 = o3;   o3 += bB;
    size_t oA3 = o3;   o3 += aB;
    size_t needT3 = o3;                // ~60 MB ; rank aliases A3

    int* deg   = (int*)(wsc + oDeg);
    int* off   = (int*)(wsc + oOff);
    int* aux   = (int*)(wsc + oAux);
    float* agg = (float*)(wsc + oAgg);

    if (ws_size >= needT2r) {
        const bool hasA = (ws_size >= needT1);
        unsigned* epk = (unsigned*)(wsc + oEp);
        float* B   = (float*)(wsc + oBn);
        float* A   = hasA ? (float*)(wsc + oAn) : nullptr;
        int* rank  = hasA ? (int*)A : (int*)(wsc + oAn);  // tier2: own 8MB past B

        hipMemsetAsync(deg, 0, (size_t)U_NODES * 4, stream);
        hipMemsetAsync(agg, 0, (size_t)U_NODES * 32 * 4, stream);

        rank_kernel<<<eBlocks, 256, 0, stream>>>(e_dst, deg, rank);
        scan_block_kernel<<<nChunks, 256, 0, stream>>>(deg, off, aux, U_NODES);
        scan_aux_kernel<<<1, 512, 0, stream>>>(aux, nChunks);
        scan_add_kernel<<<nChunks, 256, 0, stream>>>(off, aux, U_NODES);
        permute_pack_kernel<<<eBlocks, 256, 0, stream>>>(e_dst, e_src, rank, off,
                                                         e_vals, epk);
        proj_v_kernel<<<(V_NODES + 255) / 256, 256, 0, stream>>>(v, g_w1, g_b1, B);
        if (hasA) {
            proj_u_kernel<<<(U_NODES + 255) / 256, 256, 0, stream>>>(u, g_w1, A);
            edge_frag_kernel<<<eBlocks, 256, 0, stream>>>(
                A, B, epk, g_w1, g_w2, g_b2, agg);
        } else {
            edge_mfma_kernel<false><<<eBlocks, 256, 0, stream>>>(
                nullptr, B, u, epk, g_w1, g_w2, g_b2, agg);
        }
        node_kernel<<<(U_NODES + 255) / 256, 256, 0, stream>>>(
            u, agg, f_w1, f_b1, f_w2, f_b2, t_w, t_b, out);
    } else if (ws_size >= needT4) {
        const bool hasAB = (ws_size >= needT3);
        int* seid = (int*)(wsc + oSeid);
        float* B = hasAB ? (float*)(wsc + oB3) : nullptr;
        float* A = hasAB ? (float*)(wsc + oA3) : nullptr;
        int* rank = hasAB ? (int*)A : (int*)(wsc + oSeid + e4B);

        hipMemsetAsync(deg, 0, (size_t)U_NODES * 4, stream);
        hipMemsetAsync(agg, 0, (size_t)U_NODES * 32 * 4, stream);

        rank_kernel<<<eBlocks, 256, 0, stream>>>(e_dst, deg, rank);
        scan_block_kernel<<<nChunks, 256, 0, stream>>>(deg, off, aux, U_NODES);
        scan_aux_kernel<<<1, 512, 0, stream>>>(aux, nChunks);
        scan_add_kernel<<<nChunks, 256, 0, stream>>>(off, aux, U_NODES);
        scatter_kernel<<<eBlocks, 256, 0, stream>>>(e_dst, off, rank, seid);

        if (hasAB) {
            proj_v_kernel<<<(V_NODES + 255) / 256, 256, 0, stream>>>(v, g_w1, g_b1, B);
            proj_u_kernel<<<(U_NODES + 255) / 256, 256, 0, stream>>>(u, g_w1, A);
            edge_sorted_kernel<true, true><<<eBlocks, 256, 0, stream>>>(
                A, B, u, v, e_vals, e_src, e_dst, seid, g_w1, g_b1, g_w2, g_b2, agg);
        } else {
            edge_sorted_kernel<false, false><<<eBlocks, 256, 0, stream>>>(
                nullptr, nullptr, u, v, e_vals, e_src, e_dst, seid,
                g_w1, g_b1, g_w2, g_b2, agg);
        }
        node_kernel<<<(U_NODES + 255) / 256, 256, 0, stream>>>(
            u, agg, f_w1, f_b1, f_w2, f_b2, t_w, t_b, out);
    } else {
        float* agg0 = (float*)wsc;
        hipMemsetAsync(agg0, 0, (size_t)U_NODES * 32 * 4, stream);
        edge_direct_kernel<<<eBlocks, 256, 0, stream>>>(
            u, v, e_vals, e_src, e_dst, g_w1, g_b1, g_w2, g_b2, agg0);
        node_kernel<<<(U_NODES + 255) / 256, 256, 0, stream>>>(
            u, agg0, f_w1, f_b1, f_w2, f_b2, t_w, t_b, out);
    }
}